// Round 1
// baseline (534.340 us; speedup 1.0000x reference)
//
#include <hip/hip_runtime.h>

#define N_NODES 50000
#define N_EDGES 1600000
#define DIM 128

// ---------------- ws layout (bytes) ----------------
// mean  : float[N_NODES*DIM]      @ 0          (25,600,000)
// cnt   : int[N_NODES]            @ 25,600,000 (200,000)
// off   : int[N_NODES+1]          @ 25,800,000 (200,064 incl pad)
// cur   : int[N_NODES]            @ 26,000,064 (200,000)
// esort : int[N_EDGES]            @ 26,200,064 (6,400,000)
// total: 32,600,064 B

// ---- 1. histogram of destination rows ----
__global__ void hist_k(const int* __restrict__ rows, int* __restrict__ cnt) {
    int e = blockIdx.x * 256 + threadIdx.x;
    if (e < N_EDGES) atomicAdd(&cnt[rows[e]], 1);
}

// ---- 2. exclusive scan of cnt -> off, cur (single block, 1024 threads) ----
__global__ void scan_k(const int* __restrict__ cnt, int* __restrict__ off,
                       int* __restrict__ cur) {
    __shared__ int s[1024];
    const int C = 49;  // 1024*49 = 50176 >= 50000
    int t = threadIdx.x;
    int base = t * C;
    int sum = 0;
    for (int i = 0; i < C; ++i) {
        int idx = base + i;
        if (idx < N_NODES) sum += cnt[idx];
    }
    s[t] = sum;
    __syncthreads();
    for (int ofs = 1; ofs < 1024; ofs <<= 1) {
        int v = (t >= ofs) ? s[t - ofs] : 0;
        __syncthreads();
        s[t] += v;
        __syncthreads();
    }
    int run = s[t] - sum;  // exclusive prefix
    for (int i = 0; i < C; ++i) {
        int idx = base + i;
        if (idx < N_NODES) {
            off[idx] = run;
            cur[idx] = run;
            run += cnt[idx];
        }
    }
    if (t == 1023) off[N_NODES] = s[1023];
}

// ---- 3. scatter edges into CSR order (sorted by destination) ----
__global__ void scatter_k(const int* __restrict__ rows, const int* __restrict__ cols,
                          int* __restrict__ cur, int* __restrict__ esort) {
    int e = blockIdx.x * 256 + threadIdx.x;
    if (e < N_EDGES) {
        int r = rows[e];
        int p = atomicAdd(&cur[r], 1);
        esort[p] = cols[e];
    }
}

// ---- 4. per-node mean of raw seq features; one wave per node ----
__global__ void agg_k(const float* __restrict__ seq, const int* __restrict__ off,
                      const int* __restrict__ esort, float* __restrict__ mean) {
    int node = blockIdx.x * 4 + (threadIdx.x >> 6);
    int lane = threadIdx.x & 63;
    if (node >= N_NODES) return;
    int s = off[node], e = off[node + 1];
    const float2* seq2 = (const float2*)seq;
    float ax = 0.f, ay = 0.f;
    int i = s;
    for (; i + 4 <= e; i += 4) {
        int c0 = esort[i], c1 = esort[i + 1], c2 = esort[i + 2], c3 = esort[i + 3];
        float2 v0 = seq2[c0 * 64 + lane];
        float2 v1 = seq2[c1 * 64 + lane];
        float2 v2 = seq2[c2 * 64 + lane];
        float2 v3 = seq2[c3 * 64 + lane];
        ax += v0.x + v1.x + v2.x + v3.x;
        ay += v0.y + v1.y + v2.y + v3.y;
    }
    for (; i < e; ++i) {
        int c = esort[i];
        float2 v = seq2[c * 64 + lane];
        ax += v.x;
        ay += v.y;
    }
    float inv = 1.0f / ((float)(e - s) + 1e-8f);
    float2 m;
    m.x = ax * inv;
    m.y = ay * inv;
    ((float2*)mean)[node * 64 + lane] = m;
}

// ---- 5. out = PReLU(mean @ W^T); 64 rows x 128 cols per block, 8x8 per thread ----
__global__ __launch_bounds__(128) void gemm_prelu_k(const float* __restrict__ A,
                                                    const float* __restrict__ W,
                                                    const float* __restrict__ alpha_p,
                                                    float* __restrict__ out) {
    // LDS, transposed chunk layouts: As[k][r] stride 68, Bs[k][j] stride 132
    __shared__ float As[32 * 68];
    __shared__ float Bs[32 * 132];
    int t = threadIdx.x;      // 128 threads
    int tx = t & 15;          // col group: cols tx*8 .. +7
    int ty = t >> 4;          // row group: rows ty*8 .. +7  (0..7)
    int r0 = blockIdx.x * 64;

    float acc[8][8];
#pragma unroll
    for (int a = 0; a < 8; ++a)
#pragma unroll
        for (int b = 0; b < 8; ++b) acc[a][b] = 0.f;

    int c = t & 7;    // which float4 (4 k's) within the 32-k chunk
    int rb = t >> 3;  // 0..15

    for (int k0 = 0; k0 < DIM; k0 += 32) {
        // stage A chunk (64 rows x 32 k), transposed
#pragma unroll
        for (int it = 0; it < 4; ++it) {
            int r = rb + it * 16;
            int gr = r0 + r;
            float4 v = make_float4(0.f, 0.f, 0.f, 0.f);
            if (gr < N_NODES) v = ((const float4*)A)[gr * 32 + (k0 >> 2) + c];
            As[(c * 4 + 0) * 68 + r] = v.x;
            As[(c * 4 + 1) * 68 + r] = v.y;
            As[(c * 4 + 2) * 68 + r] = v.z;
            As[(c * 4 + 3) * 68 + r] = v.w;
        }
        // stage W chunk (128 j x 32 k), transposed
#pragma unroll
        for (int it = 0; it < 8; ++it) {
            int j = rb + it * 16;
            float4 v = ((const float4*)W)[j * 32 + (k0 >> 2) + c];
            Bs[(c * 4 + 0) * 132 + j] = v.x;
            Bs[(c * 4 + 1) * 132 + j] = v.y;
            Bs[(c * 4 + 2) * 132 + j] = v.z;
            Bs[(c * 4 + 3) * 132 + j] = v.w;
        }
        __syncthreads();

#pragma unroll 2
        for (int k = 0; k < 32; ++k) {
            float4 a0 = *(const float4*)&As[k * 68 + ty * 8];
            float4 a1 = *(const float4*)&As[k * 68 + ty * 8 + 4];
            float4 b0 = *(const float4*)&Bs[k * 132 + tx * 8];
            float4 b1 = *(const float4*)&Bs[k * 132 + tx * 8 + 4];
            float m[8] = {a0.x, a0.y, a0.z, a0.w, a1.x, a1.y, a1.z, a1.w};
            float w[8] = {b0.x, b0.y, b0.z, b0.w, b1.x, b1.y, b1.z, b1.w};
#pragma unroll
            for (int rr = 0; rr < 8; ++rr)
#pragma unroll
                for (int jj = 0; jj < 8; ++jj) acc[rr][jj] += m[rr] * w[jj];
        }
        __syncthreads();
    }

    float al = alpha_p[0];
#pragma unroll
    for (int rr = 0; rr < 8; ++rr) {
        int gr = r0 + ty * 8 + rr;
        if (gr < N_NODES) {
            float4 o0, o1;
            float v;
            v = acc[rr][0]; o0.x = v >= 0.f ? v : al * v;
            v = acc[rr][1]; o0.y = v >= 0.f ? v : al * v;
            v = acc[rr][2]; o0.z = v >= 0.f ? v : al * v;
            v = acc[rr][3]; o0.w = v >= 0.f ? v : al * v;
            v = acc[rr][4]; o1.x = v >= 0.f ? v : al * v;
            v = acc[rr][5]; o1.y = v >= 0.f ? v : al * v;
            v = acc[rr][6]; o1.z = v >= 0.f ? v : al * v;
            v = acc[rr][7]; o1.w = v >= 0.f ? v : al * v;
            *(float4*)&out[gr * DIM + tx * 8] = o0;
            *(float4*)&out[gr * DIM + tx * 8 + 4] = o1;
        }
    }
}

extern "C" void kernel_launch(void* const* d_in, const int* in_sizes, int n_in,
                              void* d_out, int out_size, void* d_ws, size_t ws_size,
                              hipStream_t stream) {
    const float* seq = (const float*)d_in[0];
    const float* W = (const float*)d_in[1];
    const float* alpha = (const float*)d_in[2];
    const int* rows = (const int*)d_in[3];
    const int* cols = (const int*)d_in[4];
    float* out = (float*)d_out;

    char* ws = (char*)d_ws;
    float* mean = (float*)(ws);
    int* cnt = (int*)(ws + 25600000);
    int* off = (int*)(ws + 25800000);
    int* cur = (int*)(ws + 26000064);
    int* esort = (int*)(ws + 26200064);

    hipMemsetAsync(cnt, 0, N_NODES * sizeof(int), stream);

    hist_k<<<(N_EDGES + 255) / 256, 256, 0, stream>>>(rows, cnt);
    scan_k<<<1, 1024, 0, stream>>>(cnt, off, cur);
    scatter_k<<<(N_EDGES + 255) / 256, 256, 0, stream>>>(rows, cols, cur, esort);
    agg_k<<<(N_NODES + 3) / 4, 256, 0, stream>>>(seq, off, esort, mean);
    gemm_prelu_k<<<(N_NODES + 63) / 64, 128, 0, stream>>>(mean, W, alpha, out);
}